// Round 3
// baseline (478.455 us; speedup 1.0000x reference)
//
#include <hip/hip_runtime.h>
#include <hip/hip_bf16.h>
#include <stdint.h>

#define NEGV -10000000.0f

typedef __attribute__((ext_vector_type(8))) short short8;
typedef __attribute__((ext_vector_type(4))) float f32x4;

__device__ __forceinline__ float b2f(ushort u) {
    union { float f; uint32_t i; } v; v.i = ((uint32_t)u) << 16; return v.f;
}
__device__ __forceinline__ ushort f2b(float f) {
    uint32_t x = __float_as_uint(f);
    uint32_t r = x + 0x7FFFu + ((x >> 16) & 1u);
    return (ushort)(r >> 16);
}

// ---------------- Kernel 1: GEMM1 (S = H @ Bhat^T + c) + J-softmax -> P, S_max ----
// Bhat[j][d] = U[j][d]*w_hu[d] + w_h[d];  c[j] = dot(U[j],w_u) + b
__launch_bounds__(256, 2)
__global__ void k_gemm1_softmax(const float* __restrict__ Hg,
                                const float* __restrict__ Ug,
                                const float* __restrict__ qmg,
                                const float* __restrict__ wg,
                                const float* __restrict__ bg,
                                ushort* __restrict__ Pws,
                                float* __restrict__ SmaxWs) {
    __shared__ ushort sH[64][232];   // t-tile rows as bf16, K padded to 224 (zeros)
    __shared__ ushort sB[64][232];   // Bhat rows (j) as bf16
    __shared__ ushort sP[64][72];    // P staging for coalesced out
    __shared__ float  sW[600];
    __shared__ float  sQM[64];
    __shared__ float  sC[64];

    const int tid  = threadIdx.x;
    const int lane = tid & 63;
    const int wid  = tid >> 6;
    const int n    = blockIdx.y;
    const int t0   = blockIdx.x * 64;

    for (int i = tid; i < 600; i += 256) sW[i] = wg[i];
    if (tid < 64) sQM[tid] = qmg[n * 64 + tid];
    __syncthreads();

    const float bval = bg[0];

    // build Bhat (bf16) + c[j]
    for (int r = wid; r < 64; r += 4) {
        float uwp = 0.f;
        const float* urow = Ug + (size_t)(n * 64 + r) * 200;
        for (int d = lane; d < 224; d += 64) {
            float bh = 0.f;
            if (d < 200) {
                float u = urow[d];
                bh  = u * sW[400 + d] + sW[d];
                uwp += u * sW[200 + d];
            }
            sB[r][d] = f2b(bh);
        }
        #pragma unroll
        for (int off = 32; off >= 1; off >>= 1) uwp += __shfl_xor(uwp, off);
        if (lane == 0) sC[r] = uwp + bval;
    }
    // H tile into LDS as bf16, zero K-pad
    for (int r = wid; r < 64; r += 4) {
        const float* hrow = Hg + (size_t)(n * 1024 + t0 + r) * 200;
        for (int dd = lane; dd < 232; dd += 64)
            sH[r][dd] = (dd < 200) ? f2b(hrow[dd]) : (ushort)0;
    }
    __syncthreads();

    const int g = lane >> 4, li = lane & 15;
    f32x4 acc[4];
    #pragma unroll
    for (int jt = 0; jt < 4; ++jt) acc[jt] = (f32x4){0.f, 0.f, 0.f, 0.f};

    const ushort* aRow = &sH[16 * wid + li][g * 8];
    #pragma unroll
    for (int kc = 0; kc < 7; ++kc) {
        short8 av = *(const short8*)(aRow + kc * 32);
        #pragma unroll
        for (int jt = 0; jt < 4; ++jt) {
            short8 bv = *(const short8*)(&sB[jt * 16 + li][g * 8 + kc * 32]);
            acc[jt] = __builtin_amdgcn_mfma_f32_16x16x32_bf16(av, bv, acc[jt], 0, 0, 0);
        }
    }

    float cj[4], qm[4];
    #pragma unroll
    for (int jt = 0; jt < 4; ++jt) { cj[jt] = sC[jt * 16 + li]; qm[jt] = sQM[jt * 16 + li]; }

    #pragma unroll
    for (int reg = 0; reg < 4; ++reg) {
        float x[4], y[4];
        float xm = -1e30f, ym = -1e30f;
        #pragma unroll
        for (int jt = 0; jt < 4; ++jt) {
            float s = acc[jt][reg] + cj[jt];
            x[jt] = s * qm[jt];
            y[jt] = (qm[jt] != 0.f) ? s : NEGV;
            xm = fmaxf(xm, x[jt]); ym = fmaxf(ym, y[jt]);
        }
        #pragma unroll
        for (int off = 1; off <= 8; off <<= 1) {
            xm = fmaxf(xm, __shfl_xor(xm, off));
            ym = fmaxf(ym, __shfl_xor(ym, off));
        }
        float e[4], z = 0.f, zm = 0.f;
        #pragma unroll
        for (int jt = 0; jt < 4; ++jt) {
            e[jt] = __expf(x[jt] - xm);
            z += e[jt]; zm += e[jt] * qm[jt];
        }
        #pragma unroll
        for (int off = 1; off <= 8; off <<= 1) {
            z  += __shfl_xor(z, off);
            zm += __shfl_xor(zm, off);
        }
        // p_j = e_j*m_j / (zm + 1e-13*z)   (== reference masked_softmax exactly)
        float inv = 1.f / (zm + 1e-13f * z);
        int trow = 16 * wid + g * 4 + reg;
        #pragma unroll
        for (int jt = 0; jt < 4; ++jt) sP[trow][jt * 16 + li] = f2b(e[jt] * qm[jt] * inv);
        if (li == 0) SmaxWs[n * 1024 + t0 + trow] = ym;
    }
    __syncthreads();

    uint* pout = (uint*)Pws;
    for (int idx = tid; idx < 2048; idx += 256) {
        int r = idx >> 5, c2 = idx & 31;
        uint v = *(const uint*)&sP[r][c2 * 2];
        pout[(size_t)(n * 1024 + t0 + r) * 32 + c2] = v;
    }
}

// ---------------- Kernel 2: T-softmax of S_max (mask c_mask) -> a; Hbar = a @ H ----
__launch_bounds__(256)
__global__ void k_softmaxT_hbar(const float* __restrict__ Hg,
                                const float* __restrict__ cmg,
                                const float* __restrict__ SmaxWs,
                                float* __restrict__ HbarWs) {
    __shared__ float sA[1024];
    __shared__ float red[8];
    const int tid = threadIdx.x, lane = tid & 63, wid = tid >> 6;
    const int n = blockIdx.x;

    float x[4], m[4];
    #pragma unroll
    for (int i = 0; i < 4; ++i) {
        int t = tid + 256 * i;
        float v = SmaxWs[n * 1024 + t];
        m[i] = cmg[(size_t)n * 1024 + t];
        x[i] = v * m[i];
    }
    float mx = fmaxf(fmaxf(x[0], x[1]), fmaxf(x[2], x[3]));
    #pragma unroll
    for (int off = 32; off >= 1; off >>= 1) mx = fmaxf(mx, __shfl_xor(mx, off));
    if (lane == 0) red[wid] = mx;
    __syncthreads();
    float M = fmaxf(fmaxf(red[0], red[1]), fmaxf(red[2], red[3]));
    __syncthreads();
    float e[4], z = 0.f, zm = 0.f;
    #pragma unroll
    for (int i = 0; i < 4; ++i) {
        e[i] = __expf(x[i] - M);
        z += e[i]; zm += e[i] * m[i];
    }
    #pragma unroll
    for (int off = 32; off >= 1; off >>= 1) {
        z  += __shfl_xor(z, off);
        zm += __shfl_xor(zm, off);
    }
    if (lane == 0) { red[wid] = z; red[4 + wid] = zm; }
    __syncthreads();
    float Z  = red[0] + red[1] + red[2] + red[3];
    float Zm = red[4] + red[5] + red[6] + red[7];
    float inv = 1.f / (Zm + 1e-13f * Z);
    #pragma unroll
    for (int i = 0; i < 4; ++i) sA[tid + 256 * i] = e[i] * m[i] * inv;
    __syncthreads();

    if (tid < 200) {
        const float* hp = Hg + (size_t)n * 1024 * 200 + tid;
        float acc = 0.f;
        #pragma unroll 8
        for (int t = 0; t < 1024; ++t) acc += sA[t] * hp[(size_t)t * 200];
        HbarWs[n * 200 + tid] = acc;
    }
}

// ---------------- Kernel 3: GEMM2 (U_ = P @ U) + all G writes ----------------------
__launch_bounds__(256, 2)
__global__ void k_gemm2_out(const float* __restrict__ Hg,
                            const float* __restrict__ Ug,
                            const ushort* __restrict__ Pws,
                            const float* __restrict__ HbarWs,
                            float* __restrict__ Gout) {
    // manual LDS layout with phase reuse: total 66,592 B -> 2 blocks/CU
    __shared__ __align__(16) char smem[66592];
    ushort (*sH)[208]  = (ushort(*)[208])smem;                    // 26,624 B (H as bf16)
    ushort (*sUT)[72]  = (ushort(*)[72])(smem + 26624);           // 29,952 B (U^T bf16, B operand)
    ushort (*sU2)[208] = (ushort(*)[208])(smem + 26624);          // overlay: U_ staging (26,624 B)
    ushort (*sP)[72]   = (ushort(*)[72])(smem + 26624 + 29952);   //  9,216 B
    float*  sHp        = (float*)(smem + 26624 + 29952 + 9216);   //    800 B

    const int tid = threadIdx.x, lane = tid & 63, wid = tid >> 6;
    const int n = blockIdx.y, t0 = blockIdx.x * 64;

    const uint* pin = (const uint*)Pws;
    for (int idx = tid; idx < 2048; idx += 256) {
        int r = idx >> 5, c2 = idx & 31;
        *(uint*)&sP[r][c2 * 2] = pin[(size_t)(n * 1024 + t0 + r) * 32 + c2];
    }
    for (int r = wid; r < 64; r += 4) {
        const float* hrow = Hg + (size_t)(n * 1024 + t0 + r) * 200;
        for (int dd = lane; dd < 208; dd += 64)
            sH[r][dd] = (dd < 200) ? f2b(hrow[dd]) : (ushort)0;
    }
    // transpose U into sUT[d][j] (bf16)
    for (int r = wid; r < 64; r += 4) {
        const float* urow = Ug + (size_t)(n * 64 + r) * 200;
        for (int d = lane; d < 200; d += 64) sUT[d][r] = f2b(urow[d]);
    }
    for (int idx = tid; idx < 8 * 72; idx += 256) sUT[200 + idx / 72][idx % 72] = 0;
    if (tid < 200) sHp[tid] = HbarWs[n * 200 + tid];
    __syncthreads();

    const int g = lane >> 4, li = lane & 15;
    f32x4 acc[13];
    #pragma unroll
    for (int dt = 0; dt < 13; ++dt) acc[dt] = (f32x4){0.f, 0.f, 0.f, 0.f};
    #pragma unroll
    for (int kc = 0; kc < 2; ++kc) {
        short8 av = *(const short8*)(&sP[16 * wid + li][kc * 32 + g * 8]);
        #pragma unroll
        for (int dt = 0; dt < 13; ++dt) {
            short8 bv = *(const short8*)(&sUT[dt * 16 + li][kc * 32 + g * 8]);
            acc[dt] = __builtin_amdgcn_mfma_f32_16x16x32_bf16(av, bv, acc[dt], 0, 0, 0);
        }
    }
    __syncthreads();  // everyone done reading sUT before overlay write

    #pragma unroll
    for (int dt = 0; dt < 13; ++dt) {
        int d = dt * 16 + li;
        if (d < 200) {
            #pragma unroll
            for (int reg = 0; reg < 4; ++reg) {
                int trow = 16 * wid + g * 4 + reg;
                sU2[trow][d] = f2b(acc[dt][reg]);
            }
        }
    }
    __syncthreads();

    // coalesced fp32 G writes: [H | U_ | H*U_ | H*Hbar]
    for (int r = wid; r < 64; r += 4) {
        float* orow = Gout + (size_t)(n * 1024 + t0 + r) * 800;
        if (lane < 50) {
            int d0 = lane * 4;
            uint2 hraw = *(const uint2*)&sH[r][d0];
            uint2 uraw = *(const uint2*)&sU2[r][d0];
            float4 hp  = *(const float4*)&sHp[d0];
            float h[4], uu[4];
            h[0] = b2f((ushort)(hraw.x & 0xffffu)); h[1] = b2f((ushort)(hraw.x >> 16));
            h[2] = b2f((ushort)(hraw.y & 0xffffu)); h[3] = b2f((ushort)(hraw.y >> 16));
            uu[0] = b2f((ushort)(uraw.x & 0xffffu)); uu[1] = b2f((ushort)(uraw.x >> 16));
            uu[2] = b2f((ushort)(uraw.y & 0xffffu)); uu[3] = b2f((ushort)(uraw.y >> 16));
            float hpv[4] = { hp.x, hp.y, hp.z, hp.w };

            *(float4*)(orow + d0)       = make_float4(h[0], h[1], h[2], h[3]);
            *(float4*)(orow + 200 + d0) = make_float4(uu[0], uu[1], uu[2], uu[3]);
            *(float4*)(orow + 400 + d0) = make_float4(h[0] * uu[0], h[1] * uu[1],
                                                      h[2] * uu[2], h[3] * uu[3]);
            *(float4*)(orow + 600 + d0) = make_float4(h[0] * hpv[0], h[1] * hpv[1],
                                                      h[2] * hpv[2], h[3] * hpv[3]);
        }
    }
}

extern "C" void kernel_launch(void* const* d_in, const int* in_sizes, int n_in,
                              void* d_out, int out_size, void* d_ws, size_t ws_size,
                              hipStream_t stream) {
    (void)in_sizes; (void)n_in; (void)out_size; (void)ws_size;
    const float* Hg  = (const float*)d_in[0];
    const float* Ug  = (const float*)d_in[1];
    const float* cmg = (const float*)d_in[2];
    const float* qmg = (const float*)d_in[3];
    const float* wg  = (const float*)d_in[4];
    const float* bg  = (const float*)d_in[5];
    float* Gout = (float*)d_out;

    char* ws = (char*)d_ws;
    ushort* Pws    = (ushort*)ws;                          // 64*1024*64*2 = 8,388,608 B
    float*  SmaxWs = (float*)(ws + 8388608);               // 64*1024*4    =   262,144 B
    float*  HbarWs = (float*)(ws + 8388608 + 262144);      // 64*200*4     =    51,200 B

    dim3 blk(256, 1, 1);
    dim3 grid1(16, 64, 1);
    k_gemm1_softmax<<<grid1, blk, 0, stream>>>(Hg, Ug, qmg, wg, bg, Pws, SmaxWs);
    k_softmaxT_hbar<<<dim3(64, 1, 1), blk, 0, stream>>>(Hg, cmg, SmaxWs, HbarWs);
    k_gemm2_out<<<grid1, blk, 0, stream>>>(Hg, Ug, Pws, HbarWs, Gout);
}